// Round 6
// baseline (222.598 us; speedup 1.0000x reference)
//
#include <hip/hip_runtime.h>
#include <hip/hip_bf16.h>

#define SEQ   2048
#define DIM   1024
#define NH    16
#define NKV   4
#define HDIM  64
#define BATCH 2
#define MROWS (BATCH*SEQ)   // 4096
#define NT    (SEQ/64)      // 32 kv tiles

typedef __attribute__((ext_vector_type(8))) short bf16x8;
typedef __attribute__((ext_vector_type(4))) short shortx4;
typedef __attribute__((ext_vector_type(4))) float f32x4;

static __device__ __forceinline__ short f2bf(float f) {
    unsigned u = __builtin_bit_cast(unsigned, f);
    u += 0x7fffu + ((u >> 16) & 1u);
    return (short)(u >> 16);
}

static __device__ __forceinline__ void gload16(const short* g, short* l) {
    __builtin_amdgcn_global_load_lds((const __attribute__((address_space(1))) void*)g,
                                     (__attribute__((address_space(3))) void*)l, 16, 0, 0);
}

// ---------- prepass: f32 -> bf16 contiguous ----------
__global__ __launch_bounds__(256)
void cvt_bf16(const float* __restrict__ src, short* __restrict__ dst, int n8) {
    int i = blockIdx.x * 256 + threadIdx.x;
    if (i >= n8) return;
    const float* s = src + (size_t)i * 8;
    f32x4 a = *reinterpret_cast<const f32x4*>(s);
    f32x4 b = *reinterpret_cast<const f32x4*>(s + 4);
    bf16x8 o;
    #pragma unroll
    for (int j = 0; j < 4; ++j) { o[j] = f2bf(a[j]); o[j+4] = f2bf(b[j]); }
    *reinterpret_cast<bf16x8*>(dst + (size_t)i * 8) = o;
}

// ---------- prepass: all 4 weights, W[K=1024][N] f32 -> Wt[N][1024] bf16 ----------
__global__ __launch_bounds__(256)
void tconv4(const float* __restrict__ wq, const float* __restrict__ wk,
            const float* __restrict__ wv, const float* __restrict__ wo,
            short* __restrict__ Wt, short* __restrict__ Wto) {
    __shared__ short Ts[64][72];
    const float* src; short* dst; int N;
    if      (blockIdx.z == 0) { src = wq; dst = Wt;               N = 1024; }
    else if (blockIdx.z == 1) { src = wk; dst = Wt + 1024*1024;   N = 256;  }
    else if (blockIdx.z == 2) { src = wv; dst = Wt + 1280*1024;   N = 256;  }
    else                      { src = wo; dst = Wto;              N = 1024; }
    const int n0 = blockIdx.x * 64;
    if (n0 >= N) return;
    const int k0 = blockIdx.y * 64;
    const int t = threadIdx.x;
    {
        int r = t >> 4, cg = (t & 15) * 4;
        #pragma unroll
        for (int j = 0; j < 4; ++j) {
            f32x4 v = *reinterpret_cast<const f32x4*>(&src[(size_t)(k0 + r + j*16) * N + n0 + cg]);
            #pragma unroll
            for (int q = 0; q < 4; ++q) Ts[r + j*16][cg + q] = f2bf(v[q]);
        }
    }
    __syncthreads();
    {
        int rr = t >> 3, cc = (t & 7) * 8;
        #pragma unroll
        for (int j = 0; j < 2; ++j) {
            bf16x8 o;
            #pragma unroll
            for (int q = 0; q < 8; ++q) o[q] = Ts[cc + q][rr + j*32];
            *reinterpret_cast<bf16x8*>(&dst[(size_t)(n0 + rr + j*32) * 1024 + k0 + cc]) = o;
        }
    }
}

// ---------- m97-style GEMM, 128M x 64N tile: A[4096][1024] bf16 × Bt[N][1024] bf16 ----------
template<int MODE>
__global__ __launch_bounds__(256)
void mm97(const short* __restrict__ A, const short* __restrict__ Bt,
          short* __restrict__ q_out, short* __restrict__ k_out, short* __restrict__ v_out,
          float* __restrict__ f_out)
{
    __shared__ short As[128][32];
    __shared__ short Bs[64][32];
    const int m0 = blockIdx.y * 128, n0 = blockIdx.x * 64;
    const int t = threadIdx.x, wv = t >> 6, l = t & 63, lg = l >> 4, li = l & 15;
    const int wr = wv >> 1, wc = wv & 1;
    f32x4 acc[4][2] = {};

    const short* ga = A  + (size_t)(m0 + (t >> 2)) * 1024 + (t & 3) * 8;
    const short* gb = Bt + (size_t)(n0 + (t >> 2)) * 1024 + (t & 3) * 8;
    short* la = (short*)As + t * 8;
    short* lb = (short*)Bs + t * 8;

    for (int k0 = 0; k0 < 1024; k0 += 32) {
        gload16(ga + k0,            la);
        gload16(ga + 64*1024 + k0,  la + 2048);
        gload16(gb + k0,            lb);
        __syncthreads();
        bf16x8 av[4], bv[2];
        #pragma unroll
        for (int m = 0; m < 4; ++m)
            av[m] = *reinterpret_cast<const bf16x8*>(&As[wr*64 + m*16 + li][lg*8]);
        #pragma unroll
        for (int n = 0; n < 2; ++n)
            bv[n] = *reinterpret_cast<const bf16x8*>(&Bs[wc*32 + n*16 + li][lg*8]);
        #pragma unroll
        for (int m = 0; m < 4; ++m)
            #pragma unroll
            for (int n = 0; n < 2; ++n)
                acc[m][n] = __builtin_amdgcn_mfma_f32_16x16x32_bf16(av[m], bv[n], acc[m][n], 0, 0, 0);
        __syncthreads();
    }

    #pragma unroll
    for (int m = 0; m < 4; ++m) {
        #pragma unroll
        for (int n = 0; n < 2; ++n) {
            #pragma unroll
            for (int r = 0; r < 4; ++r) {
                int row = m0 + wr*64 + m*16 + lg*4 + r;
                int col = n0 + wc*32 + n*16 + li;
                float v = acc[m][n][r];
                if constexpr (MODE == 0) {
                    int b = row >> 11, s = row & (SEQ-1);
                    if (col < 1024) {
                        q_out[(((size_t)((b*NH + (col>>6))*SEQ + s)) << 6) + (col & 63)] = f2bf(v);
                    } else if (col < 1280) {
                        int c1 = col - 1024;
                        k_out[(((size_t)((b*NKV + (c1>>6))*SEQ + s)) << 6) + (c1 & 63)] = f2bf(v);
                    } else {
                        int c1 = col - 1280;
                        v_out[((size_t)((b*NKV + (c1>>6))*HDIM + (c1 & 63)))*SEQ + s] = f2bf(v);
                    }
                } else {
                    f_out[(size_t)row * 1024 + col] = v;
                }
            }
        }
    }
}

// ---------- flash attention, batch-fused, high-occupancy ----------
// grid (S/32, NH); 4 waves: wave w = (batch w>>1, q-half w&1), 16 q-rows each.
// Single-buffered K/V, reg-staged (T14): wave w stages tile KV[w]
// (w=0: K_b0, 1: V_b0, 2: K_b1, 3: V_b1). LDS 40 KB -> 4 blocks/CU.
// K slot-permuted (slot s holds key (s&15)*4+(s>>4)) so pb loads are dwordx4
// and P writes are b64; V natural so the permutation cancels in PV.
__global__ __launch_bounds__(256, 4)
void gqa_attn(const short* __restrict__ Qh, const short* __restrict__ Kh,
              const short* __restrict__ Vt, const float* __restrict__ pb,
              short* __restrict__ AO)
{
    __shared__ short KV[4][64][64];    // [K_b0|V_b0|K_b1|V_b1][slot][d], XOR-swizzled
    __shared__ short Ps[4][16][64];    // per-wave P [q][key], XOR-swizzled
    const int q0 = blockIdx.x * 32;
    const int hq = blockIdx.y, hkv = hq >> 2;
    const int t = threadIdx.x, w = t >> 6, l = t & 63, lg = l >> 4, li = l & 15;
    const int bw = w >> 1, hw = w & 1;
    const int swl = (li & 7) << 4;

    const short* Qp = Qh + ((size_t)(bw*NH + hq)*SEQ)*HDIM;

    // ---- staging role: wave w fills KV[w]; 8 x 16B per lane per tile
    const int lr8 = l >> 3;
    const int bb  = (l & 7) ^ lr8;             // pre-swizzled 16B chunk
    const int role_v = w & 1, role_b = w >> 1;
    const short* gsrc;
    size_t strideTile;
    if (role_v) {
        gsrc = Vt + ((size_t)(role_b*NKV + hkv)*HDIM)*SEQ + (size_t)lr8*SEQ + bb*8;
        strideTile = 64;
    } else {
        gsrc = Kh + ((size_t)(role_b*NKV + hkv)*SEQ)*HDIM + (size_t)(4*lr8)*HDIM + bb*8;
        strideTile = 64*HDIM;
    }
    char* const ldsW = (char*)&KV[w][0][0] + lr8*128 + (l & 7)*16;

#define SRC_OFF(j) (role_v ? (size_t)(8*(j))*SEQ : (size_t)(32*((j)&1) + ((j)>>1))*HDIM)

    bf16x8 qa[2];
    {
        int qr = q0 + hw*16 + li;
        qa[0] = *reinterpret_cast<const bf16x8*>(&Qp[(size_t)qr*HDIM + lg*8]);
        qa[1] = *reinterpret_cast<const bf16x8*>(&Qp[(size_t)qr*HDIM + 32 + lg*8]);
    }

    // pb rows q0+hw*16+lg*4+r, cols li*4..li*4+3 (contiguous via key-permute)
    const float* pbp = pb + ((size_t)hq*SEQ + q0 + hw*16 + lg*4)*SEQ + li*4;

    const char* kbase = (const char*)&KV[w & ~1][0][0];
    const char* vbase = kbase + 8192;
    char* PsW = (char*)Ps + w*2048;

    f32x4 oacc[4] = {};
    float lrow[4] = {};
    f32x4 pbq[4];
    bf16x8 sv[8];

    // ---- prologue: tile 0
    #pragma unroll
    for (int j = 0; j < 8; ++j) sv[j] = *reinterpret_cast<const bf16x8*>(gsrc + SRC_OFF(j));
    gsrc += strideTile;
    #pragma unroll
    for (int r = 0; r < 4; ++r) pbq[r] = *reinterpret_cast<const f32x4*>(pbp + (size_t)r*SEQ);
    #pragma unroll
    for (int j = 0; j < 8; ++j) *reinterpret_cast<bf16x8*>(ldsW + j*1024) = sv[j];
    asm volatile("s_waitcnt lgkmcnt(0)" ::: "memory");
    __builtin_amdgcn_s_barrier();

    #pragma unroll 1
    for (int kt = 0; kt < NT; ++kt) {
        // issue next tile's global loads first; they land under QK+softmax+PV
        if (kt < NT - 1) {
            #pragma unroll
            for (int j = 0; j < 8; ++j) sv[j] = *reinterpret_cast<const bf16x8*>(gsrc + SRC_OFF(j));
            gsrc += strideTile;
            __builtin_amdgcn_sched_barrier(0);
        }

        // QK^T: 16q × 64key; fragment c = keys li*4+c (permuted slots)
        f32x4 sacc[4] = {};
        __builtin_amdgcn_s_setprio(1);
        #pragma unroll
        for (int c = 0; c < 4; ++c) {
            const char* kb = kbase + (c*16 + li)*128;
            bf16x8 kv0 = *(const bf16x8*)(kb + ((     lg*16) ^ swl));
            bf16x8 kv1 = *(const bf16x8*)(kb + ((64 + lg*16) ^ swl));
            sacc[c] = __builtin_amdgcn_mfma_f32_16x16x32_bf16(qa[0], kv0, sacc[c], 0, 0, 0);
            sacc[c] = __builtin_amdgcn_mfma_f32_16x16x32_bf16(qa[1], kv1, sacc[c], 0, 0, 0);
        }
        __builtin_amdgcn_s_setprio(0);

        // fixed-max softmax: p = exp2(qk/8*L + pb*L - 12L); sum deferred
        #pragma unroll
        for (int r = 0; r < 4; ++r) {
            char* pw = PsW + (lg*4 + r)*128;
            const int swp = ((lg*4 + r) & 7) << 4;
            float rs = 0.f;
            shortx4 pk;
            #pragma unroll
            for (int c = 0; c < 4; ++c) {
                float p = exp2f(fmaf(sacc[c][r], 0.1803368801f,
                                fmaf(pbq[r][c], 1.442695041f, -17.31234049f)));
                rs += p;
                pk[c] = f2bf(p);
            }
            *(shortx4*)(pw + ((li*8) ^ swp)) = pk;
            lrow[r] += rs;
        }

        if (kt < NT - 1) {
            #pragma unroll
            for (int r = 0; r < 4; ++r)
                pbq[r] = *reinterpret_cast<const f32x4*>(pbp + (size_t)r*SEQ + (kt + 1)*64);
            __builtin_amdgcn_sched_barrier(0);
        }

        // PV: oacc[c2] += P[16x64] * V^T[64d x 64key]
        __builtin_amdgcn_s_setprio(1);
        #pragma unroll
        for (int h = 0; h < 2; ++h) {
            bf16x8 pa = *(const bf16x8*)(PsW + li*128 + ((h*64 + lg*16) ^ swl));
            #pragma unroll
            for (int c2 = 0; c2 < 4; ++c2) {
                bf16x8 vb = *(const bf16x8*)(vbase + (c2*16 + li)*128 + ((h*64 + lg*16) ^ swl));
                oacc[c2] = __builtin_amdgcn_mfma_f32_16x16x32_bf16(pa, vb, oacc[c2], 0, 0, 0);
            }
        }
        __builtin_amdgcn_s_setprio(0);

        // handoff: readers done -> write next tile -> writers done
        asm volatile("s_waitcnt lgkmcnt(0)" ::: "memory");
        __builtin_amdgcn_s_barrier();
        if (kt < NT - 1) {
            #pragma unroll
            for (int j = 0; j < 8; ++j) *reinterpret_cast<bf16x8*>(ldsW + j*1024) = sv[j];
            asm volatile("s_waitcnt lgkmcnt(0)" ::: "memory");
        }
        __builtin_amdgcn_s_barrier();
    }
#undef SRC_OFF

    // epilogue: reduce row-sums across the 16 lanes holding each row, store AO
    #pragma unroll
    for (int r = 0; r < 4; ++r) {
        float s = lrow[r];
        s += __shfl_xor(s, 1); s += __shfl_xor(s, 2);
        s += __shfl_xor(s, 4); s += __shfl_xor(s, 8);
        float inv = 1.0f / s;
        int qrow = q0 + hw*16 + lg*4 + r;
        short* ao = AO + (((size_t)(bw*SEQ + qrow)) << 10) + hq*HDIM;
        #pragma unroll
        for (int c2 = 0; c2 < 4; ++c2)
            ao[c2*16 + li] = f2bf(oacc[c2][r] * inv);
    }
}

extern "C" void kernel_launch(void* const* d_in, const int* in_sizes, int n_in,
                              void* d_out, int out_size, void* d_ws, size_t ws_size,
                              hipStream_t stream)
{
    const float* x    = (const float*)d_in[0];
    const float* wq   = (const float*)d_in[1];
    const float* wk   = (const float*)d_in[2];
    const float* wvp  = (const float*)d_in[3];
    const float* wo   = (const float*)d_in[4];
    const float* pb   = (const float*)d_in[5];

    char* ws = (char*)d_ws;
    short* Xb  = (short*)(ws);                      // [4096][1024] bf16, 8 MB
    short* AO  = (short*)(ws);                      // aliases Xb (Xb dead before attn writes AO)
    short* Wt  = (short*)(ws + 8388608);            // [1536][1024] bf16, 3 MB (Q|K|V transposed)
    short* Wto = (short*)(ws + 11534336);           // [1024][1024] bf16, 2 MB
    short* Qh  = (short*)(ws + 13631488);           // [B,NH,S,64]  bf16, 8 MB
    short* Kh  = (short*)(ws + 22020096);           // [B,NKV,S,64] bf16, 2 MB
    short* Vt  = (short*)(ws + 24117248);           // [B,NKV,64,S] bf16, 2 MB

    dim3 blk(256);
    cvt_bf16<<<dim3(MROWS*DIM/8/256), blk, 0, stream>>>(x, Xb, MROWS*DIM/8);
    tconv4<<<dim3(16, 16, 4), blk, 0, stream>>>(wq, wk, wvp, wo, Wt, Wto);
    mm97<0><<<dim3(24, 32), blk, 0, stream>>>(Xb, Wt,  Qh, Kh, Vt, nullptr);
    gqa_attn<<<dim3(SEQ/32, NH), blk, 0, stream>>>(Qh, Kh, Vt, pb, AO);
    mm97<1><<<dim3(16, 32), blk, 0, stream>>>(AO, Wto, nullptr, nullptr, nullptr, (float*)d_out);
}

// Round 7
// 155.962 us; speedup vs baseline: 1.4273x; 1.4273x over previous
//
#include <hip/hip_runtime.h>
#include <hip/hip_bf16.h>

#define SEQ   2048
#define DIM   1024
#define NH    16
#define NKV   4
#define HDIM  64
#define BATCH 2
#define MROWS (BATCH*SEQ)   // 4096
#define NT    (SEQ/64)      // 32 kv tiles

typedef __attribute__((ext_vector_type(8))) short bf16x8;
typedef __attribute__((ext_vector_type(4))) short shortx4;
typedef __attribute__((ext_vector_type(4))) float f32x4;

static __device__ __forceinline__ short f2bf(float f) {
    unsigned u = __builtin_bit_cast(unsigned, f);
    u += 0x7fffu + ((u >> 16) & 1u);
    return (short)(u >> 16);
}

static __device__ __forceinline__ void gload16(const short* g, short* l) {
    __builtin_amdgcn_global_load_lds((const __attribute__((address_space(1))) void*)g,
                                     (__attribute__((address_space(3))) void*)l, 16, 0, 0);
}

// ---------- prepass: f32 -> bf16 contiguous ----------
__global__ __launch_bounds__(256)
void cvt_bf16(const float* __restrict__ src, short* __restrict__ dst, int n8) {
    int i = blockIdx.x * 256 + threadIdx.x;
    if (i >= n8) return;
    const float* s = src + (size_t)i * 8;
    f32x4 a = *reinterpret_cast<const f32x4*>(s);
    f32x4 b = *reinterpret_cast<const f32x4*>(s + 4);
    bf16x8 o;
    #pragma unroll
    for (int j = 0; j < 4; ++j) { o[j] = f2bf(a[j]); o[j+4] = f2bf(b[j]); }
    *reinterpret_cast<bf16x8*>(dst + (size_t)i * 8) = o;
}

// ---------- prepass: all 4 weights, W[K=1024][N] f32 -> Wt[N][1024] bf16 ----------
__global__ __launch_bounds__(256)
void tconv4(const float* __restrict__ wq, const float* __restrict__ wk,
            const float* __restrict__ wv, const float* __restrict__ wo,
            short* __restrict__ Wt, short* __restrict__ Wto) {
    __shared__ short Ts[64][72];
    const float* src; short* dst; int N;
    if      (blockIdx.z == 0) { src = wq; dst = Wt;               N = 1024; }
    else if (blockIdx.z == 1) { src = wk; dst = Wt + 1024*1024;   N = 256;  }
    else if (blockIdx.z == 2) { src = wv; dst = Wt + 1280*1024;   N = 256;  }
    else                      { src = wo; dst = Wto;              N = 1024; }
    const int n0 = blockIdx.x * 64;
    if (n0 >= N) return;
    const int k0 = blockIdx.y * 64;
    const int t = threadIdx.x;
    {
        int r = t >> 4, cg = (t & 15) * 4;
        #pragma unroll
        for (int j = 0; j < 4; ++j) {
            f32x4 v = *reinterpret_cast<const f32x4*>(&src[(size_t)(k0 + r + j*16) * N + n0 + cg]);
            #pragma unroll
            for (int q = 0; q < 4; ++q) Ts[r + j*16][cg + q] = f2bf(v[q]);
        }
    }
    __syncthreads();
    {
        int rr = t >> 3, cc = (t & 7) * 8;
        #pragma unroll
        for (int j = 0; j < 2; ++j) {
            bf16x8 o;
            #pragma unroll
            for (int q = 0; q < 8; ++q) o[q] = Ts[cc + q][rr + j*32];
            *reinterpret_cast<bf16x8*>(&dst[(size_t)(n0 + rr + j*32) * 1024 + k0 + cc]) = o;
        }
    }
}

// ---------- m97-style GEMM, 128M x 64N tile: A[4096][1024] bf16 × Bt[N][1024] bf16 ----------
template<int MODE>
__global__ __launch_bounds__(256)
void mm97(const short* __restrict__ A, const short* __restrict__ Bt,
          short* __restrict__ q_out, short* __restrict__ k_out, short* __restrict__ v_out,
          float* __restrict__ f_out)
{
    __shared__ short As[128][32];
    __shared__ short Bs[64][32];
    const int m0 = blockIdx.y * 128, n0 = blockIdx.x * 64;
    const int t = threadIdx.x, wv = t >> 6, l = t & 63, lg = l >> 4, li = l & 15;
    const int wr = wv >> 1, wc = wv & 1;
    f32x4 acc[4][2] = {};

    const short* ga = A  + (size_t)(m0 + (t >> 2)) * 1024 + (t & 3) * 8;
    const short* gb = Bt + (size_t)(n0 + (t >> 2)) * 1024 + (t & 3) * 8;
    short* la = (short*)As + t * 8;
    short* lb = (short*)Bs + t * 8;

    for (int k0 = 0; k0 < 1024; k0 += 32) {
        gload16(ga + k0,            la);
        gload16(ga + 64*1024 + k0,  la + 2048);
        gload16(gb + k0,            lb);
        __syncthreads();
        bf16x8 av[4], bv[2];
        #pragma unroll
        for (int m = 0; m < 4; ++m)
            av[m] = *reinterpret_cast<const bf16x8*>(&As[wr*64 + m*16 + li][lg*8]);
        #pragma unroll
        for (int n = 0; n < 2; ++n)
            bv[n] = *reinterpret_cast<const bf16x8*>(&Bs[wc*32 + n*16 + li][lg*8]);
        #pragma unroll
        for (int m = 0; m < 4; ++m)
            #pragma unroll
            for (int n = 0; n < 2; ++n)
                acc[m][n] = __builtin_amdgcn_mfma_f32_16x16x32_bf16(av[m], bv[n], acc[m][n], 0, 0, 0);
        __syncthreads();
    }

    #pragma unroll
    for (int m = 0; m < 4; ++m) {
        #pragma unroll
        for (int n = 0; n < 2; ++n) {
            #pragma unroll
            for (int r = 0; r < 4; ++r) {
                int row = m0 + wr*64 + m*16 + lg*4 + r;
                int col = n0 + wc*32 + n*16 + li;
                float v = acc[m][n][r];
                if constexpr (MODE == 0) {
                    int b = row >> 11, s = row & (SEQ-1);
                    if (col < 1024) {
                        q_out[(((size_t)((b*NH + (col>>6))*SEQ + s)) << 6) + (col & 63)] = f2bf(v);
                    } else if (col < 1280) {
                        int c1 = col - 1024;
                        k_out[(((size_t)((b*NKV + (c1>>6))*SEQ + s)) << 6) + (c1 & 63)] = f2bf(v);
                    } else {
                        int c1 = col - 1280;
                        v_out[((size_t)((b*NKV + (c1>>6))*HDIM + (c1 & 63)))*SEQ + s] = f2bf(v);
                    }
                } else {
                    f_out[(size_t)row * 1024 + col] = v;
                }
            }
        }
    }
}

// ---------- flash attention: grid (S/128, B*NH); 4 waves × 32 q-rows ----------
// gload_lds double-buffered K/V (pre-swizzled source), pb prefetched to regs,
// counted vmcnt + raw barriers. K slot-permuted (slot s holds key (s&15)*4+(s>>4))
// so pb loads are dwordx4 and P writes b64; V natural so permutation cancels in PV.
// 32 q-rows/wave: K/V frag reads amortized over 2 q-frags (20 b128 / 32 MFMA).
__global__ __launch_bounds__(256, 3)
void gqa_attn(const short* __restrict__ Qh, const short* __restrict__ Kh,
              const short* __restrict__ Vt, const float* __restrict__ pb,
              short* __restrict__ AO)
{
    __shared__ short Ks[2][64][64];    // [buf][slot][d], swizzled, slot-permuted
    __shared__ short Vs[2][64][64];    // [buf][d][key],  swizzled, natural
    __shared__ short Ps[4][32][64];    // per-wave P [q][key], swizzled, natural
    const int q0 = blockIdx.x * 128;
    const int bh = blockIdx.y, hq = bh >> 1, b = bh & 1, hkv = hq >> 2;
    const int t = threadIdx.x, wv = t >> 6, l = t & 63, lg = l >> 4, li = l & 15;
    const int swl = (li & 7) << 4;

    const short* Qp = Qh + ((size_t)(b*NH  + hq )*SEQ)*HDIM;
    const short* Kp = Kh + ((size_t)(b*NKV + hkv)*SEQ)*HDIM;
    const short* Vp = Vt + ((size_t)(b*NKV + hkv)*HDIM)*SEQ;

    // staging: lane l covers slot (wv*16 + l>>3) [+8], 16B chunk (l&7)^(l>>3)
    const int lr8 = l >> 3;
    const int bb  = (l & 7) ^ lr8;
    // K permuted: slot wv*16+lr8 holds key lr8*4+wv; slot+8 holds key +32
    const int kOff0 = (lr8*4 + wv)*HDIM + bb*8;
    const int kOff1 = kOff0 + 32*HDIM;
    // V natural: d-row wv*16+lr8
    const size_t vOff0 = (size_t)(wv*16 + lr8)*SEQ + bb*8;
    const size_t vOff1 = vOff0 + (size_t)8*SEQ;

    bf16x8 qa[2][2];
    #pragma unroll
    for (int f = 0; f < 2; ++f) {
        int qr = q0 + wv*32 + f*16 + li;
        qa[f][0] = *reinterpret_cast<const bf16x8*>(&Qp[(size_t)qr*HDIM + lg*8]);
        qa[f][1] = *reinterpret_cast<const bf16x8*>(&Qp[(size_t)qr*HDIM + 32 + lg*8]);
    }

    // pb rows q0+wv*32+f*16+lg*4+r, cols li*4..li*4+3 (contiguous via key-permute)
    const float* pbp = pb + ((size_t)hq*SEQ + q0 + wv*32 + lg*4)*SEQ + li*4;

    f32x4 oacc[2][4] = {};
    float lrow[2][4] = {};
    f32x4 pbq[2][4];
    char* PsW = (char*)Ps + wv*4096;

#define STAGE(nxt, kk) do { \
    gload16(Kp + (size_t)(kk)*HDIM + kOff0, &Ks[nxt][wv*16][0]);     \
    gload16(Kp + (size_t)(kk)*HDIM + kOff1, &Ks[nxt][wv*16 + 8][0]); \
    gload16(Vp + (size_t)(kk) + vOff0,      &Vs[nxt][wv*16][0]);     \
    gload16(Vp + (size_t)(kk) + vOff1,      &Vs[nxt][wv*16 + 8][0]); \
} while (0)

#define PBLOAD(kk) do { \
    _Pragma("unroll") \
    for (int f = 0; f < 2; ++f) \
        _Pragma("unroll") \
        for (int r = 0; r < 4; ++r) \
            pbq[f][r] = *reinterpret_cast<const f32x4*>(pbp + (size_t)(f*16 + r)*SEQ + (kk)); \
} while (0)

    // prologue: tile 0
    STAGE(0, 0);
    PBLOAD(0);
    asm volatile("s_waitcnt vmcnt(0)" ::: "memory");
    __builtin_amdgcn_s_barrier();

    #pragma unroll 1
    for (int kt = 0; kt < NT; ++kt) {
        const int cur = kt & 1;
        const char* kbase = (const char*)&Ks[cur][0][0];
        const char* vbase = (const char*)&Vs[cur][0][0];

        if (kt < NT - 1) {
            STAGE(cur ^ 1, (kt + 1)*64);
            __builtin_amdgcn_sched_barrier(0);
        }

        // QK^T: 32q × 64key; K-frags reused across both q-frags
        f32x4 sacc[2][4] = {};
        __builtin_amdgcn_s_setprio(1);
        #pragma unroll
        for (int c = 0; c < 4; ++c) {
            const char* kb = kbase + (c*16 + li)*128;
            bf16x8 kv0 = *(const bf16x8*)(kb + ((     lg*16) ^ swl));
            bf16x8 kv1 = *(const bf16x8*)(kb + ((64 + lg*16) ^ swl));
            #pragma unroll
            for (int f = 0; f < 2; ++f) {
                sacc[f][c] = __builtin_amdgcn_mfma_f32_16x16x32_bf16(qa[f][0], kv0, sacc[f][c], 0, 0, 0);
                sacc[f][c] = __builtin_amdgcn_mfma_f32_16x16x32_bf16(qa[f][1], kv1, sacc[f][c], 0, 0, 0);
            }
        }
        __builtin_amdgcn_s_setprio(0);

        // fixed-max softmax: p = exp2(qk/8*L2E + pb*L2E - 12*L2E); sum deferred
        #pragma unroll
        for (int f = 0; f < 2; ++f) {
            #pragma unroll
            for (int r = 0; r < 4; ++r) {
                int prow = f*16 + lg*4 + r;
                char* pw = PsW + prow*128;
                const int swp = (prow & 7) << 4;
                float rs = 0.f;
                shortx4 pk;
                #pragma unroll
                for (int c = 0; c < 4; ++c) {
                    float p = exp2f(fmaf(sacc[f][c][r], 0.1803368801f,
                                    fmaf(pbq[f][r][c], 1.442695041f, -17.31234049f)));
                    rs += p;
                    pk[c] = f2bf(p);
                }
                *(shortx4*)(pw + ((li*8) ^ swp)) = pk;
                lrow[f][r] += rs;
            }
        }

        if (kt < NT - 1) {
            PBLOAD((kt + 1)*64);
            __builtin_amdgcn_sched_barrier(0);
        }

        // PV: oacc[f][c2] += P[32x64] * V^T[64d x 64key]
        __builtin_amdgcn_s_setprio(1);
        #pragma unroll
        for (int h = 0; h < 2; ++h) {
            bf16x8 pa[2];
            #pragma unroll
            for (int f = 0; f < 2; ++f)
                pa[f] = *(const bf16x8*)(PsW + (f*16 + li)*128 + ((h*64 + lg*16) ^ swl));
            #pragma unroll
            for (int c2 = 0; c2 < 4; ++c2) {
                bf16x8 vb = *(const bf16x8*)(vbase + (c2*16 + li)*128 + ((h*64 + lg*16) ^ swl));
                #pragma unroll
                for (int f = 0; f < 2; ++f)
                    oacc[f][c2] = __builtin_amdgcn_mfma_f32_16x16x32_bf16(pa[f], vb, oacc[f][c2], 0, 0, 0);
            }
        }
        __builtin_amdgcn_s_setprio(0);

        __builtin_amdgcn_sched_barrier(0);
        // outstanding: 4 stage (older) + 8 pb (newer) -> drain stage, keep pb in flight
        asm volatile("s_waitcnt vmcnt(8)" ::: "memory");
        __builtin_amdgcn_s_barrier();
    }
#undef STAGE
#undef PBLOAD

    // epilogue: reduce row-sums across the 16 lanes holding each row, store AO
    #pragma unroll
    for (int f = 0; f < 2; ++f) {
        #pragma unroll
        for (int r = 0; r < 4; ++r) {
            float s = lrow[f][r];
            s += __shfl_xor(s, 1); s += __shfl_xor(s, 2);
            s += __shfl_xor(s, 4); s += __shfl_xor(s, 8);
            float inv = 1.0f / s;
            int qrow = q0 + wv*32 + f*16 + lg*4 + r;
            short* ao = AO + (((size_t)(b*SEQ + qrow)) << 10) + hq*HDIM;
            #pragma unroll
            for (int c2 = 0; c2 < 4; ++c2)
                ao[c2*16 + li] = f2bf(oacc[f][c2][r] * inv);
        }
    }
}

extern "C" void kernel_launch(void* const* d_in, const int* in_sizes, int n_in,
                              void* d_out, int out_size, void* d_ws, size_t ws_size,
                              hipStream_t stream)
{
    const float* x    = (const float*)d_in[0];
    const float* wq   = (const float*)d_in[1];
    const float* wk   = (const float*)d_in[2];
    const float* wvp  = (const float*)d_in[3];
    const float* wo   = (const float*)d_in[4];
    const float* pb   = (const float*)d_in[5];

    char* ws = (char*)d_ws;
    short* Xb  = (short*)(ws);                      // [4096][1024] bf16, 8 MB
    short* AO  = (short*)(ws);                      // aliases Xb (Xb dead before attn writes AO)
    short* Wt  = (short*)(ws + 8388608);            // [1536][1024] bf16, 3 MB (Q|K|V transposed)
    short* Wto = (short*)(ws + 11534336);           // [1024][1024] bf16, 2 MB
    short* Qh  = (short*)(ws + 13631488);           // [B,NH,S,64]  bf16, 8 MB
    short* Kh  = (short*)(ws + 22020096);           // [B,NKV,S,64] bf16, 2 MB
    short* Vt  = (short*)(ws + 24117248);           // [B,NKV,64,S] bf16, 2 MB

    dim3 blk(256);
    cvt_bf16<<<dim3(MROWS*DIM/8/256), blk, 0, stream>>>(x, Xb, MROWS*DIM/8);
    tconv4<<<dim3(16, 16, 4), blk, 0, stream>>>(wq, wk, wvp, wo, Wt, Wto);
    mm97<0><<<dim3(24, 32), blk, 0, stream>>>(Xb, Wt,  Qh, Kh, Vt, nullptr);
    gqa_attn<<<dim3(SEQ/128, BATCH*NH), blk, 0, stream>>>(Qh, Kh, Vt, pb, AO);
    mm97<1><<<dim3(16, 32), blk, 0, stream>>>(AO, Wto, nullptr, nullptr, nullptr, (float*)d_out);
}